// Round 1
// baseline (392.614 us; speedup 1.0000x reference)
//
#include <hip/hip_runtime.h>

// MipCubemapEncoder: B=4194304 dirs -> 4 cubemap levels (L=4,16,64,256),
// 6-dim bilinear lookup per level, output (B, 24) fp32.
//
// Strategy: pre-transpose params from [face][dim][L][L] to [face][y][x][8]
// (dim-innermost, padded to 8 floats = 32B) in d_ws so each bilinear corner
// is 2 aligned float4 loads hitting a single 64B cache line. Main kernel:
// 1 thread per point, 6x float4 coalesced output stores.

constexpr float EPS_F = 1e-12f;
constexpr int LVL_L[4] = {4, 16, 64, 256};

__global__ __launch_bounds__(256) void transpose_params_kernel(
    const float* __restrict__ src, float* __restrict__ dst, int L, int n) {
  int tid = blockIdx.x * blockDim.x + threadIdx.x;
  if (tid >= n) return;                 // n = 6*L*L, tid = face*L*L + y*L + x
  int LL = L * L;
  int face = tid / LL;
  int rem = tid - face * LL;
  float v[6];
#pragma unroll
  for (int d = 0; d < 6; ++d) v[d] = src[(size_t)(face * 6 + d) * LL + rem];
  float4* o = reinterpret_cast<float4*>(dst + (size_t)tid * 8);
  o[0] = make_float4(v[0], v[1], v[2], v[3]);
  o[1] = make_float4(v[4], v[5], 0.f, 0.f);
}

template <bool TRANS>
__global__ __launch_bounds__(256) void encode_kernel(
    const float* __restrict__ inputs,
    const float* __restrict__ p0, const float* __restrict__ p1,
    const float* __restrict__ p2, const float* __restrict__ p3,
    const float* __restrict__ fail, float* __restrict__ out, int B) {
  int b = blockIdx.x * blockDim.x + threadIdx.x;
  if (b >= B) return;

  float x = inputs[3 * b + 0];
  float y = inputs[3 * b + 1];
  float z = inputs[3 * b + 2];
  float ax = fabsf(x), ay = fabsf(y), az = fabsf(z);
  bool is_x = (ax >= ay) && (ax >= az);
  bool is_y = !is_x && (ay >= az);
  float ma = fmaxf(fmaxf(ax, ay), az);

  int face;
  float sc, tc;
  if (is_x) {
    face = (x >= 0.f) ? 0 : 1;
    sc = (x >= 0.f) ? -z : z;
    tc = -y;
  } else if (is_y) {
    face = (y >= 0.f) ? 2 : 3;
    sc = x;
    tc = (y >= 0.f) ? z : -z;
  } else {
    face = (z >= 0.f) ? 4 : 5;
    sc = (z >= 0.f) ? x : -x;
    tc = -y;
  }
  float safe = fmaxf(ma, EPS_F);
  float u = 0.5f * (sc / safe + 1.0f);
  float v = 0.5f * (tc / safe + 1.0f);
  bool valid = ma > EPS_F;

  const float* ps[4] = {p0, p1, p2, p3};
  float res[24];

#pragma unroll
  for (int l = 0; l < 4; ++l) {
    const int L = LVL_L[l];
    float fu = u * (float)L - 0.5f;
    float fv = v * (float)L - 0.5f;
    float x0f = floorf(fu);
    float y0f = floorf(fv);
    float wx = fu - x0f;
    float wy = fv - y0f;
    int xi = (int)x0f;
    int yi = (int)y0f;
    int x0 = min(max(xi, 0), L - 1);
    int x1 = min(max(xi + 1, 0), L - 1);
    int y0 = min(max(yi, 0), L - 1);
    int y1 = min(max(yi + 1, 0), L - 1);
    const float* p = ps[l];

    if (TRANS) {
      // layout: [face][y][x][8] — corner = 2 aligned float4 loads (32B)
      size_t i00 = ((size_t)(face * L + y0) * L + x0) * 8;
      size_t i01 = ((size_t)(face * L + y0) * L + x1) * 8;
      size_t i10 = ((size_t)(face * L + y1) * L + x0) * 8;
      size_t i11 = ((size_t)(face * L + y1) * L + x1) * 8;
      float4 a00 = *reinterpret_cast<const float4*>(p + i00);
      float4 b00 = *reinterpret_cast<const float4*>(p + i00 + 4);
      float4 a01 = *reinterpret_cast<const float4*>(p + i01);
      float4 b01 = *reinterpret_cast<const float4*>(p + i01 + 4);
      float4 a10 = *reinterpret_cast<const float4*>(p + i10);
      float4 b10 = *reinterpret_cast<const float4*>(p + i10 + 4);
      float4 a11 = *reinterpret_cast<const float4*>(p + i11);
      float4 b11 = *reinterpret_cast<const float4*>(p + i11 + 4);
      float v00[6] = {a00.x, a00.y, a00.z, a00.w, b00.x, b00.y};
      float v01[6] = {a01.x, a01.y, a01.z, a01.w, b01.x, b01.y};
      float v10[6] = {a10.x, a10.y, a10.z, a10.w, b10.x, b10.y};
      float v11[6] = {a11.x, a11.y, a11.z, a11.w, b11.x, b11.y};
#pragma unroll
      for (int d = 0; d < 6; ++d) {
        float top = v00[d] * (1.f - wx) + v01[d] * wx;
        float bot = v10[d] * (1.f - wx) + v11[d] * wx;
        res[l * 6 + d] = top * (1.f - wy) + bot * wy;
      }
    } else {
      // raw layout: [face][dim][L][L]
      size_t LL = (size_t)L * L;
#pragma unroll
      for (int d = 0; d < 6; ++d) {
        const float* pd = p + (size_t)(face * 6 + d) * LL;
        float v00 = pd[(size_t)y0 * L + x0];
        float v01 = pd[(size_t)y0 * L + x1];
        float v10 = pd[(size_t)y1 * L + x0];
        float v11 = pd[(size_t)y1 * L + x1];
        float top = v00 * (1.f - wx) + v01 * wx;
        float bot = v10 * (1.f - wx) + v11 * wx;
        res[l * 6 + d] = top * (1.f - wy) + bot * wy;
      }
    }
  }

  if (!valid) {
#pragma unroll
    for (int l = 0; l < 4; ++l)
#pragma unroll
      for (int d = 0; d < 6; ++d) res[l * 6 + d] = fail[d];
  }

  float4* o = reinterpret_cast<float4*>(out + (size_t)b * 24);
#pragma unroll
  for (int q = 0; q < 6; ++q) {
    o[q] = make_float4(res[q * 4 + 0], res[q * 4 + 1], res[q * 4 + 2],
                       res[q * 4 + 3]);
  }
}

extern "C" void kernel_launch(void* const* d_in, const int* in_sizes, int n_in,
                              void* d_out, int out_size, void* d_ws,
                              size_t ws_size, hipStream_t stream) {
  const float* inputs = (const float*)d_in[0];
  const float* params[4] = {(const float*)d_in[1], (const float*)d_in[2],
                            (const float*)d_in[3], (const float*)d_in[4]};
  const float* fail = (const float*)d_in[5];
  float* out = (float*)d_out;
  int B = in_sizes[0] / 3;

  // workspace layout: per level, 6*L*L*8 floats
  size_t offs[4];
  size_t tot = 0;
  for (int i = 0; i < 4; ++i) {
    offs[i] = tot;
    tot += (size_t)6 * LVL_L[i] * LVL_L[i] * 8;
  }
  size_t need_bytes = tot * sizeof(float);

  dim3 blk(256);
  dim3 grid((B + 255) / 256);

  if (ws_size >= need_bytes) {
    float* ws = (float*)d_ws;
    for (int i = 0; i < 4; ++i) {
      int L = LVL_L[i];
      int n = 6 * L * L;
      transpose_params_kernel<<<(n + 255) / 256, 256, 0, stream>>>(
          params[i], ws + offs[i], L, n);
    }
    encode_kernel<true><<<grid, blk, 0, stream>>>(
        inputs, ws + offs[0], ws + offs[1], ws + offs[2], ws + offs[3], fail,
        out, B);
  } else {
    encode_kernel<false><<<grid, blk, 0, stream>>>(
        inputs, params[0], params[1], params[2], params[3], fail, out, B);
  }
}